// Round 9
// baseline (302.409 us; speedup 1.0000x reference)
//
#include <hip/hip_runtime.h>
#include <hip/hip_bf16.h>
#include <hip/hip_fp16.h>
#include <math.h>

// GCN link prediction. R9: counting sort by dest column + CSR gather agg.
// This round: int4-vectorized edge reads in sort phases, 8-deep unrolled
// gather loops (batch independent loads -> halve latency exposures),
// nontemporal streaming loads so ebuf2/row/col traffic doesn't evict the
// L2-resident fp16 tables, 2 edges/thread in k_score.
//   deg[v] = incount(col==v)+1 ; dinv = rsqrt(deg)
//   ts[v]  = (h[v]@W)*dinv[v]          (fp16 gather tables, L2-resident)
//   h'[c]  = act(dinv[c]*(sum_{e:col=c} ts[row_e] + ts[c]) + b)
//   score  = sigmoid(dot(h2[row], h2[col]))

#define BSH 8
#define BSZ 256            // nodes per bucket
#define PA_BLOCKS 256      // edge chunks (pB1 scan width)

#define NTL(p) __builtin_nontemporal_load(p)

// ---- Phase A: per-(chunk,bucket) histogram -> M[b][NBUK] ----
__global__ __launch_bounds__(512) void pA(const int* __restrict__ col,
                                          int* __restrict__ M, int E, int CH, int NBUK) {
    extern __shared__ int hist[];
    const int t = threadIdx.x, b = blockIdx.x;
    for (int i = t; i < NBUK; i += 512) hist[i] = 0;
    __syncthreads();
    const int s = b * CH, e = min(E, s + CH);
    const int n4 = (e - s) >> 2;                 // CH % 4 == 0 -> s is 16B-aligned
    const int4* c4 = (const int4*)(col + s);
    for (int i = t; i < n4; i += 512) {
        int4 c = c4[i];
        atomicAdd(&hist[c.x >> BSH], 1);
        atomicAdd(&hist[c.y >> BSH], 1);
        atomicAdd(&hist[c.z >> BSH], 1);
        atomicAdd(&hist[c.w >> BSH], 1);
    }
    for (int i = s + (n4 << 2) + t; i < e; i += 512) atomicAdd(&hist[col[i] >> BSH], 1);
    __syncthreads();
    for (int i = t; i < NBUK; i += 512) M[b * NBUK + i] = hist[i];
}

// ---- Phase B1: per-bucket exclusive scan over the 256 chunks ----
__global__ __launch_bounds__(256) void pB1(int* __restrict__ M, int* __restrict__ T, int NBUK) {
    __shared__ int s[256];
    const int t = threadIdx.x, k = blockIdx.x;
    int own = M[t * NBUK + k];
    s[t] = own;
    __syncthreads();
    for (int d = 1; d < 256; d <<= 1) {
        int add = (t >= d) ? s[t - d] : 0;
        __syncthreads();
        s[t] += add;
        __syncthreads();
    }
    M[t * NBUK + k] = s[t] - own;
    if (t == 255) T[k] = s[255];
}

// ---- Phase B2: exclusive scan of bucket totals -> S[0..NBUK]; also start[N]=E ----
__global__ __launch_bounds__(512) void pB2(const int* __restrict__ T, int* __restrict__ S,
                                           int* __restrict__ start, int NBUK, int N, int E) {
    __shared__ int s[512];
    const int t = threadIdx.x;
    int own = (t < NBUK) ? T[t] : 0;
    s[t] = own;
    __syncthreads();
    for (int d = 1; d < 512; d <<= 1) {
        int add = (t >= d) ? s[t - d] : 0;
        __syncthreads();
        s[t] += add;
        __syncthreads();
    }
    if (t < NBUK) S[t] = s[t] - own;
    if (t == 511) S[NBUK] = s[511];
    if (t == 0) start[N] = E;
}

// ---- Phase C: bucket-place edges into ebuf, packed (lcol<<17)|row ----
__global__ __launch_bounds__(512) void pC(const int* __restrict__ row, const int* __restrict__ col,
                                          const int* __restrict__ M, const int* __restrict__ S,
                                          unsigned int* __restrict__ ebuf, int E, int CH, int NBUK) {
    extern __shared__ int cur[];
    const int t = threadIdx.x, b = blockIdx.x;
    for (int i = t; i < NBUK; i += 512) cur[i] = S[i] + M[b * NBUK + i];
    __syncthreads();
    const int s = b * CH, e = min(E, s + CH);
    const int n4 = (e - s) >> 2;
    const int4* c4 = (const int4*)(col + s);
    const int4* r4 = (const int4*)(row + s);
    for (int i = t; i < n4; i += 512) {
        int4 c = c4[i];
        int4 r = r4[i];
        int p0 = atomicAdd(&cur[c.x >> BSH], 1);
        ebuf[p0] = ((unsigned int)(c.x & (BSZ - 1)) << 17) | (unsigned int)r.x;
        int p1 = atomicAdd(&cur[c.y >> BSH], 1);
        ebuf[p1] = ((unsigned int)(c.y & (BSZ - 1)) << 17) | (unsigned int)r.y;
        int p2 = atomicAdd(&cur[c.z >> BSH], 1);
        ebuf[p2] = ((unsigned int)(c.z & (BSZ - 1)) << 17) | (unsigned int)r.z;
        int p3 = atomicAdd(&cur[c.w >> BSH], 1);
        ebuf[p3] = ((unsigned int)(c.w & (BSZ - 1)) << 17) | (unsigned int)r.w;
    }
    for (int i = s + (n4 << 2) + t; i < e; i += 512) {
        int c = col[i], r = row[i];
        int p = atomicAdd(&cur[c >> BSH], 1);
        ebuf[p] = ((unsigned int)(c & (BSZ - 1)) << 17) | (unsigned int)r;
    }
}

// ---- Phase C2: in-bucket counting sort by local col; emits dinv and CSR start ----
__global__ __launch_bounds__(256) void pC2(const unsigned int* __restrict__ ebuf,
                                           const int* __restrict__ S,
                                           unsigned int* __restrict__ ebuf2,
                                           float* __restrict__ dinv,
                                           int* __restrict__ start, int N) {
    __shared__ int h[BSZ], sc[BSZ], cur[BSZ];
    const int t = threadIdx.x, k = blockIdx.x;
    h[t] = 0;
    __syncthreads();
    const int s = S[k], e = S[k + 1];
    for (int i = s + t; i < e; i += 512) {
        unsigned int a0 = ebuf[i];
        bool v1 = (i + 256) < e;
        unsigned int a1 = v1 ? ebuf[i + 256] : 0u;
        atomicAdd(&h[a0 >> 17], 1);
        if (v1) atomicAdd(&h[a1 >> 17], 1);
    }
    __syncthreads();
    sc[t] = h[t];
    __syncthreads();
    for (int d = 1; d < 256; d <<= 1) {
        int add = (t >= d) ? sc[t - d] : 0;
        __syncthreads();
        sc[t] += add;
        __syncthreads();
    }
    cur[t] = sc[t] - h[t];             // exclusive scan
    const int v = (k << BSH) + t;
    if (v < N) {
        dinv[v] = rsqrtf((float)h[t] + 1.0f);
        start[v] = s + cur[t];
    }
    __syncthreads();
    for (int i = s + t; i < e; i += 512) {
        unsigned int w0 = ebuf[i];
        bool v1 = (i + 256) < e;
        unsigned int w1 = v1 ? ebuf[i + 256] : 0u;
        int p0 = atomicAdd(&cur[w0 >> 17], 1);
        ebuf2[s + p0] = w0;
        if (v1) {
            int p1 = atomicAdd(&cur[w1 >> 17], 1);
            ebuf2[s + p1] = w1;
        }
    }
}

// ---- GEMM1: ts1h[v] = half((x[v] @ W1) * dinv[v]) ----
__global__ __launch_bounds__(256) void k_gemm1(
    const float* __restrict__ x, const float* __restrict__ W1,
    const float* __restrict__ dinv, __half* __restrict__ ts, int N) {
    __shared__ float wsT[16 * 132];
    const int tid = threadIdx.x;
    for (int idx = tid; idx < 2048; idx += 256) {
        int k = idx >> 4, c = idx & 15;
        wsT[c * 132 + k] = W1[idx];
    }
    __syncthreads();
    const int n = blockIdx.x * 256 + tid;
    if (n >= N) return;
    const float4* xr = (const float4*)(x + (size_t)n * 128);
    float acc[16];
    #pragma unroll
    for (int c = 0; c < 16; ++c) acc[c] = 0.f;
    #pragma unroll 4
    for (int k4 = 0; k4 < 32; ++k4) {
        float4 a = xr[k4];
        #pragma unroll
        for (int c = 0; c < 16; ++c) {
            const float4 w = *(const float4*)&wsT[c * 132 + k4 * 4];
            acc[c] = fmaf(a.x, w.x, fmaf(a.y, w.y, fmaf(a.z, w.z, fmaf(a.w, w.w, acc[c]))));
        }
    }
    float dv = dinv[n];
    union { __half h[16]; uint4 u[2]; } o;
    #pragma unroll
    for (int c = 0; c < 16; ++c) o.h[c] = __float2half(acc[c] * dv);
    uint4* dst = (uint4*)(ts + (size_t)n * 16);
    dst[0] = o.u[0]; dst[1] = o.u[1];
}

// ---- Layer-1 aggregation: 8 lanes/node, 8-deep unrolled CSR gather,
//      fused bias/ReLU + 16x16 W2 via width-8 shuffles ----
__global__ __launch_bounds__(256) void pGat1(
    const unsigned int* __restrict__ ebuf2, const int* __restrict__ start,
    const __half2* __restrict__ tsv, const float* __restrict__ dinv,
    const float* __restrict__ b1, const float* __restrict__ W2,
    __half2* __restrict__ ts2v, int N) {
    __shared__ float w2s[256];
    const int tid = threadIdx.x;
    w2s[tid] = W2[tid];
    __syncthreads();
    const int l = tid & 7;                 // channel pair: c0=2l, c1=2l+1
    const int v = blockIdx.x * 32 + (tid >> 3);
    if (v >= N) return;
    const int s = start[v], e = start[v + 1];
    float sx = 0.f, sy = 0.f;
    int i = s;
    for (; i + 8 <= e; i += 8) {
        unsigned int w0 = NTL(&ebuf2[i]);
        unsigned int w1 = NTL(&ebuf2[i + 1]);
        unsigned int w2 = NTL(&ebuf2[i + 2]);
        unsigned int w3 = NTL(&ebuf2[i + 3]);
        unsigned int w4 = NTL(&ebuf2[i + 4]);
        unsigned int w5 = NTL(&ebuf2[i + 5]);
        unsigned int w6 = NTL(&ebuf2[i + 6]);
        unsigned int w7 = NTL(&ebuf2[i + 7]);
        float2 f0 = __half22float2(tsv[(size_t)(w0 & 0x1FFFF) * 8 + l]);
        float2 f1 = __half22float2(tsv[(size_t)(w1 & 0x1FFFF) * 8 + l]);
        float2 f2 = __half22float2(tsv[(size_t)(w2 & 0x1FFFF) * 8 + l]);
        float2 f3 = __half22float2(tsv[(size_t)(w3 & 0x1FFFF) * 8 + l]);
        float2 f4 = __half22float2(tsv[(size_t)(w4 & 0x1FFFF) * 8 + l]);
        float2 f5 = __half22float2(tsv[(size_t)(w5 & 0x1FFFF) * 8 + l]);
        float2 f6 = __half22float2(tsv[(size_t)(w6 & 0x1FFFF) * 8 + l]);
        float2 f7 = __half22float2(tsv[(size_t)(w7 & 0x1FFFF) * 8 + l]);
        sx += ((f0.x + f1.x) + (f2.x + f3.x)) + ((f4.x + f5.x) + (f6.x + f7.x));
        sy += ((f0.y + f1.y) + (f2.y + f3.y)) + ((f4.y + f5.y) + (f6.y + f7.y));
    }
    for (; i + 4 <= e; i += 4) {
        unsigned int w0 = NTL(&ebuf2[i]);
        unsigned int w1 = NTL(&ebuf2[i + 1]);
        unsigned int w2 = NTL(&ebuf2[i + 2]);
        unsigned int w3 = NTL(&ebuf2[i + 3]);
        float2 f0 = __half22float2(tsv[(size_t)(w0 & 0x1FFFF) * 8 + l]);
        float2 f1 = __half22float2(tsv[(size_t)(w1 & 0x1FFFF) * 8 + l]);
        float2 f2 = __half22float2(tsv[(size_t)(w2 & 0x1FFFF) * 8 + l]);
        float2 f3 = __half22float2(tsv[(size_t)(w3 & 0x1FFFF) * 8 + l]);
        sx += (f0.x + f1.x) + (f2.x + f3.x);
        sy += (f0.y + f1.y) + (f2.y + f3.y);
    }
    for (; i < e; ++i) {
        unsigned int w = NTL(&ebuf2[i]);
        float2 f = __half22float2(tsv[(size_t)(w & 0x1FFFF) * 8 + l]);
        sx += f.x; sy += f.y;
    }
    const float dv = dinv[v];
    float2 sf = __half22float2(tsv[(size_t)v * 8 + l]);
    float hx = fmaxf(dv * (sx + sf.x) + b1[2 * l],     0.f);
    float hy = fmaxf(dv * (sy + sf.y) + b1[2 * l + 1], 0.f);
    float ox = 0.f, oy = 0.f;
    #pragma unroll
    for (int j = 0; j < 8; ++j) {
        float ax = __shfl(hx, j, 8);       // channel 2j
        float ay = __shfl(hy, j, 8);       // channel 2j+1
        ox = fmaf(ax, w2s[(2 * j) * 16 + 2 * l],     fmaf(ay, w2s[(2 * j + 1) * 16 + 2 * l],     ox));
        oy = fmaf(ax, w2s[(2 * j) * 16 + 2 * l + 1], fmaf(ay, w2s[(2 * j + 1) * 16 + 2 * l + 1], oy));
    }
    ts2v[(size_t)v * 8 + l] = __halves2half2(__float2half(dv * ox), __float2half(dv * oy));
}

// ---- Layer-2 aggregation: 8 lanes/node CSR gather + final bias -> h2 ----
__global__ __launch_bounds__(256) void pGat2(
    const unsigned int* __restrict__ ebuf2, const int* __restrict__ start,
    const __half2* __restrict__ tsv, const float* __restrict__ dinv,
    const float* __restrict__ b2, __half2* __restrict__ h2v, int N) {
    const int tid = threadIdx.x;
    const int l = tid & 7;
    const int v = blockIdx.x * 32 + (tid >> 3);
    if (v >= N) return;
    const int s = start[v], e = start[v + 1];
    float sx = 0.f, sy = 0.f;
    int i = s;
    for (; i + 8 <= e; i += 8) {
        unsigned int w0 = NTL(&ebuf2[i]);
        unsigned int w1 = NTL(&ebuf2[i + 1]);
        unsigned int w2 = NTL(&ebuf2[i + 2]);
        unsigned int w3 = NTL(&ebuf2[i + 3]);
        unsigned int w4 = NTL(&ebuf2[i + 4]);
        unsigned int w5 = NTL(&ebuf2[i + 5]);
        unsigned int w6 = NTL(&ebuf2[i + 6]);
        unsigned int w7 = NTL(&ebuf2[i + 7]);
        float2 f0 = __half22float2(tsv[(size_t)(w0 & 0x1FFFF) * 8 + l]);
        float2 f1 = __half22float2(tsv[(size_t)(w1 & 0x1FFFF) * 8 + l]);
        float2 f2 = __half22float2(tsv[(size_t)(w2 & 0x1FFFF) * 8 + l]);
        float2 f3 = __half22float2(tsv[(size_t)(w3 & 0x1FFFF) * 8 + l]);
        float2 f4 = __half22float2(tsv[(size_t)(w4 & 0x1FFFF) * 8 + l]);
        float2 f5 = __half22float2(tsv[(size_t)(w5 & 0x1FFFF) * 8 + l]);
        float2 f6 = __half22float2(tsv[(size_t)(w6 & 0x1FFFF) * 8 + l]);
        float2 f7 = __half22float2(tsv[(size_t)(w7 & 0x1FFFF) * 8 + l]);
        sx += ((f0.x + f1.x) + (f2.x + f3.x)) + ((f4.x + f5.x) + (f6.x + f7.x));
        sy += ((f0.y + f1.y) + (f2.y + f3.y)) + ((f4.y + f5.y) + (f6.y + f7.y));
    }
    for (; i + 4 <= e; i += 4) {
        unsigned int w0 = NTL(&ebuf2[i]);
        unsigned int w1 = NTL(&ebuf2[i + 1]);
        unsigned int w2 = NTL(&ebuf2[i + 2]);
        unsigned int w3 = NTL(&ebuf2[i + 3]);
        float2 f0 = __half22float2(tsv[(size_t)(w0 & 0x1FFFF) * 8 + l]);
        float2 f1 = __half22float2(tsv[(size_t)(w1 & 0x1FFFF) * 8 + l]);
        float2 f2 = __half22float2(tsv[(size_t)(w2 & 0x1FFFF) * 8 + l]);
        float2 f3 = __half22float2(tsv[(size_t)(w3 & 0x1FFFF) * 8 + l]);
        sx += (f0.x + f1.x) + (f2.x + f3.x);
        sy += (f0.y + f1.y) + (f2.y + f3.y);
    }
    for (; i < e; ++i) {
        unsigned int w = NTL(&ebuf2[i]);
        float2 f = __half22float2(tsv[(size_t)(w & 0x1FFFF) * 8 + l]);
        sx += f.x; sy += f.y;
    }
    float2 sf = __half22float2(tsv[(size_t)v * 8 + l]);
    const float dv = dinv[v];
    h2v[(size_t)v * 8 + l] = __halves2half2(
        __float2half(dv * (sx + sf.x) + b2[2 * l]),
        __float2half(dv * (sy + sf.y) + b2[2 * l + 1]));
}

// ---- Edge scores: 2 edges per thread ----
__global__ void k_score(const int* __restrict__ row, const int* __restrict__ col,
                        const __half* __restrict__ h2h, float* __restrict__ out, int E) {
    int e0 = (blockIdx.x * 256 + threadIdx.x) * 2;
    if (e0 >= E) return;
    const int n = min(2, E - e0);
    #pragma unroll
    for (int q = 0; q < 2; ++q) {
        if (q < n) {
            int e = e0 + q;
            int r = NTL(&row[e]), c = NTL(&col[e]);
            union { uint4 u[2]; __half2 h[8]; } a, b;
            const uint4* pa = (const uint4*)(h2h + (size_t)r * 16);
            const uint4* pb = (const uint4*)(h2h + (size_t)c * 16);
            a.u[0] = pa[0]; a.u[1] = pa[1];
            b.u[0] = pb[0]; b.u[1] = pb[1];
            float d = 0.f;
            #pragma unroll
            for (int i = 0; i < 8; ++i) {
                float2 fa = __half22float2(a.h[i]);
                float2 fb = __half22float2(b.h[i]);
                d = fmaf(fa.x, fb.x, fmaf(fa.y, fb.y, d));
            }
            __builtin_nontemporal_store(1.0f / (1.0f + __expf(-d)), &out[e]);
        }
    }
}

// ---------------- Fallback (R2 atomic path) ----------------
__global__ void k_countf(const int* __restrict__ col, float* __restrict__ deg, int E) {
    int e = blockIdx.x * 256 + threadIdx.x;
    if (e < E) atomicAdd(&deg[col[e]], 1.0f);
}
__global__ void k_dinvf(float* __restrict__ dinv, int N) {
    int v = blockIdx.x * 256 + threadIdx.x;
    if (v < N) dinv[v] = rsqrtf(dinv[v] + 1.0f);
}
__global__ __launch_bounds__(256) void k_gemm1f(
    const float* __restrict__ x, const float* __restrict__ W1,
    const float* __restrict__ dinv, float* __restrict__ ts, int N) {
    __shared__ float wsT[16 * 132];
    const int tid = threadIdx.x;
    for (int idx = tid; idx < 2048; idx += 256) {
        int k = idx >> 4, c = idx & 15;
        wsT[c * 132 + k] = W1[idx];
    }
    __syncthreads();
    const int n = blockIdx.x * 256 + tid;
    if (n >= N) return;
    const float4* xr = (const float4*)(x + (size_t)n * 128);
    float acc[16];
    #pragma unroll
    for (int c = 0; c < 16; ++c) acc[c] = 0.f;
    for (int k4 = 0; k4 < 32; ++k4) {
        float4 a = xr[k4];
        #pragma unroll
        for (int c = 0; c < 16; ++c) {
            const float4 w = *(const float4*)&wsT[c * 132 + k4 * 4];
            acc[c] = fmaf(a.x, w.x, fmaf(a.y, w.y, fmaf(a.z, w.z, fmaf(a.w, w.w, acc[c]))));
        }
    }
    float dv = dinv[n];
    float4* o = (float4*)(ts + (size_t)n * 16);
    #pragma unroll
    for (int q = 0; q < 4; ++q)
        o[q] = make_float4(acc[4*q] * dv, acc[4*q+1] * dv, acc[4*q+2] * dv, acc[4*q+3] * dv);
}
__global__ void k_scatter(const int* __restrict__ row, const int* __restrict__ col,
                          const float* __restrict__ ts, float* __restrict__ acc, int E) {
    int g = blockIdx.x * 256 + threadIdx.x;
    int e = g >> 4, c = g & 15;
    if (e < E) atomicAdd(&acc[(size_t)col[e] * 16 + c], ts[(size_t)row[e] * 16 + c]);
}
__global__ void k_finalize(float* __restrict__ acc, const float* __restrict__ ts,
                           const float* __restrict__ dinv, const float* __restrict__ b,
                           int N, int relu) {
    int g = blockIdx.x * 256 + threadIdx.x;
    int v = g >> 4, c = g & 15;
    if (v < N) {
        float h = dinv[v] * (acc[g] + ts[g]) + b[c];
        if (relu) h = fmaxf(h, 0.f);
        acc[g] = h;
    }
}
__global__ __launch_bounds__(256) void k_gemm2f(
    const float* __restrict__ h1, const float* __restrict__ W2,
    const float* __restrict__ dinv, float* __restrict__ ts2, int N) {
    __shared__ float hs[16 * 17];
    __shared__ float ws2[256];
    const int tid = threadIdx.x;
    const int base = blockIdx.x * 16;
    if (tid < 64) ((float4*)ws2)[tid] = ((const float4*)W2)[tid];
    if (tid >= 64 && tid < 128) {
        int t2 = tid - 64;
        float4 v4 = ((const float4*)(h1 + (size_t)base * 16))[t2];
        float* d = &hs[(t2 >> 2) * 17 + (t2 & 3) * 4];
        d[0] = v4.x; d[1] = v4.y; d[2] = v4.z; d[3] = v4.w;
    }
    __syncthreads();
    const int r = tid >> 4, c = tid & 15;
    float a = 0.f;
    #pragma unroll
    for (int kk = 0; kk < 16; ++kk) a = fmaf(hs[r * 17 + kk], ws2[kk * 16 + c], a);
    ts2[(size_t)(base + r) * 16 + c] = a * dinv[base + r];
}
__global__ void k_scoref(const int* __restrict__ row, const int* __restrict__ col,
                         const float* __restrict__ h2, float* __restrict__ out, int E) {
    int e = blockIdx.x * 256 + threadIdx.x;
    if (e < E) {
        const float4* a = (const float4*)(h2 + (size_t)row[e] * 16);
        const float4* b = (const float4*)(h2 + (size_t)col[e] * 16);
        float d = 0.f;
        #pragma unroll
        for (int i = 0; i < 4; ++i) {
            float4 u = a[i], v = b[i];
            d += u.x * v.x + u.y * v.y + u.z * v.z + u.w * v.w;
        }
        out[e] = 1.0f / (1.0f + __expf(-d));
    }
}

extern "C" void kernel_launch(void* const* d_in, const int* in_sizes, int n_in,
                              void* d_out, int out_size, void* d_ws, size_t ws_size,
                              hipStream_t stream) {
    const float* x  = (const float*)d_in[0];
    const int*   ei = (const int*)d_in[1];
    const float* W1 = (const float*)d_in[2];
    const float* b1 = (const float*)d_in[3];
    const float* W2 = (const float*)d_in[4];
    const float* b2 = (const float*)d_in[5];

    const int N = in_sizes[0] / 128;   // 100000
    const int E = in_sizes[1] / 2;     // 3200000
    const int* row = ei;
    const int* col = ei + E;
    float* out = (float*)d_out;

    const int NBUK = (N + BSZ - 1) / BSZ;   // 391
    // CH multiple of 4 so every chunk start is 16B-aligned for int4 loads
    const int CH = (((E + PA_BLOCKS - 1) / PA_BLOCKS) + 3) & ~3;

    char* ws = (char*)d_ws;
    size_t off = 0;
    auto alloc = [&](size_t bytes) { void* p = ws + off; off += (bytes + 255) & ~(size_t)255; return p; };
    float*  dinv  = (float*)alloc((size_t)N * 4);
    __half* ts1h  = (__half*)alloc((size_t)N * 32);    // also h2h after pGat1
    __half* ts2h  = (__half*)alloc((size_t)N * 32);
    int*    start = (int*)alloc((size_t)(N + 1) * 4);
    int*    M     = (int*)alloc((size_t)PA_BLOCKS * NBUK * 4);
    int*    T     = (int*)alloc((size_t)NBUK * 4);
    int*    S     = (int*)alloc((size_t)(NBUK + 1) * 4);
    unsigned int* ebuf  = (unsigned int*)alloc((size_t)E * 4);
    unsigned int* ebuf2 = (unsigned int*)alloc((size_t)E * 4);
    const size_t need = off;    // ~34 MB at N=100k, E=3.2M

    if (N <= 131072 && NBUK <= 512 && ws_size >= need) {
        const size_t ldsA = (size_t)NBUK * 4;
        pA <<<PA_BLOCKS, 512, ldsA, stream>>>(col, M, E, CH, NBUK);
        pB1<<<NBUK, 256, 0, stream>>>(M, T, NBUK);
        pB2<<<1, 512, 0, stream>>>(T, S, start, NBUK, N, E);
        pC <<<PA_BLOCKS, 512, ldsA, stream>>>(row, col, M, S, ebuf, E, CH, NBUK);
        pC2<<<NBUK, 256, 0, stream>>>(ebuf, S, ebuf2, dinv, start, N);
        k_gemm1<<<(N + 255) / 256, 256, 0, stream>>>(x, W1, dinv, ts1h, N);
        pGat1<<<(N + 31) / 32, 256, 0, stream>>>(ebuf2, start, (const __half2*)ts1h, dinv, b1, W2,
                                                 (__half2*)ts2h, N);
        __half* h2h = ts1h;   // ts1h dead after pGat1
        pGat2<<<(N + 31) / 32, 256, 0, stream>>>(ebuf2, start, (const __half2*)ts2h, dinv, b2,
                                                 (__half2*)h2h, N);
        k_score<<<(E / 2 + 255) / 256, 256, 0, stream>>>(row, col, h2h, out, E);
    } else {
        // R2 fallback, fp32 buffers carved independently
        float* dinvF = (float*)ws;
        float* ts1F  = (float*)(ws + (size_t)N * 4);
        float* ts2F  = (float*)(ws + (size_t)N * 4 + (size_t)N * 64);
        hipMemsetAsync(dinvF, 0, (size_t)N * 4, stream);
        hipMemsetAsync(ts2F, 0, (size_t)N * 64, stream);
        k_countf<<<(E + 255) / 256, 256, 0, stream>>>(col, dinvF, E);
        k_dinvf<<<(N + 255) / 256, 256, 0, stream>>>(dinvF, N);
        k_gemm1f<<<(N + 255) / 256, 256, 0, stream>>>(x, W1, dinvF, ts1F, N);
        k_scatter<<<(E * 16) / 256, 256, 0, stream>>>(row, col, ts1F, ts2F, E);
        k_finalize<<<(N * 16 + 255) / 256, 256, 0, stream>>>(ts2F, ts1F, dinvF, b1, N, 1);
        k_gemm2f<<<N / 16, 256, 0, stream>>>(ts2F, W2, dinvF, ts1F, N);
        hipMemsetAsync(ts2F, 0, (size_t)N * 64, stream);
        k_scatter<<<(E * 16) / 256, 256, 0, stream>>>(row, col, ts1F, ts2F, E);
        k_finalize<<<(N * 16 + 255) / 256, 256, 0, stream>>>(ts2F, ts1F, dinvF, b2, N, 0);
        k_scoref<<<(E + 255) / 256, 256, 0, stream>>>(row, col, ts2F, out, E);
    }
}

// Round 10
// 265.118 us; speedup vs baseline: 1.1407x; 1.1407x over previous
//
#include <hip/hip_runtime.h>
#include <hip/hip_bf16.h>
#include <hip/hip_fp16.h>
#include <math.h>

// GCN link prediction. R10: counting sort by dest col with LDS-STAGED bucket
// placement (pC writes coalesced runs instead of random 4B scatters -> kills
// ~10x write amplification), 1000-chunk parallelism in sort phases, CSR gather
// aggregation (R8-proven form: 8 lanes/node, half2, 4-unroll, no NT hints),
// 1-edge/thread scorer (R9's 2-edge/NT variant regressed; reverted).
//   deg[v] = incount(col==v)+1 ; dinv = rsqrt(deg)
//   ts[v]  = (h[v]@W)*dinv[v]          (fp16 gather tables, L2-resident)
//   h'[c]  = act(dinv[c]*(sum_{e:col=c} ts[row_e] + ts[c]) + b)
//   score  = sigmoid(dot(h2[row], h2[col]))

#define BSH 9
#define BSZ 512            // nodes per bucket -> NBUK = 196 (<= 256)
#define MAXCH 3200         // edges per chunk (multiple of 4)
#define MAXCHUNKS 1024

// ---- Phase A: per-(chunk,bucket) histogram -> M[b][NBUK] ----
__global__ __launch_bounds__(256) void pA(const int* __restrict__ col,
                                          int* __restrict__ M, int E, int CH, int NBUK) {
    __shared__ int hist[256];
    const int t = threadIdx.x, b = blockIdx.x;
    hist[t] = 0;
    __syncthreads();
    const int s = b * CH, e = min(E, s + CH);
    const int n4 = (e - s) >> 2;                 // CH % 4 == 0 -> 16B-aligned
    const int4* c4 = (const int4*)(col + s);
    for (int i = t; i < n4; i += 256) {
        int4 c = c4[i];
        atomicAdd(&hist[c.x >> BSH], 1);
        atomicAdd(&hist[c.y >> BSH], 1);
        atomicAdd(&hist[c.z >> BSH], 1);
        atomicAdd(&hist[c.w >> BSH], 1);
    }
    for (int i = s + (n4 << 2) + t; i < e; i += 256) atomicAdd(&hist[col[i] >> BSH], 1);
    __syncthreads();
    for (int i = t; i < NBUK; i += 256) M[b * NBUK + i] = hist[i];
}

// ---- Phase B1: per-bucket exclusive scan over CN chunks (CN <= 1024) ----
__global__ __launch_bounds__(1024) void pB1(int* __restrict__ M, int* __restrict__ T,
                                            int NBUK, int CN) {
    __shared__ int s[1024];
    const int t = threadIdx.x, k = blockIdx.x;
    int own = (t < CN) ? M[t * NBUK + k] : 0;
    s[t] = own;
    __syncthreads();
    for (int d = 1; d < 1024; d <<= 1) {
        int add = (t >= d) ? s[t - d] : 0;
        __syncthreads();
        s[t] += add;
        __syncthreads();
    }
    if (t < CN) M[t * NBUK + k] = s[t] - own;
    if (t == 1023) T[k] = s[1023];
}

// ---- Phase B2: exclusive scan of bucket totals -> S[0..NBUK]; also start[N]=E ----
__global__ __launch_bounds__(512) void pB2(const int* __restrict__ T, int* __restrict__ S,
                                           int* __restrict__ start, int NBUK, int N, int E) {
    __shared__ int s[512];
    const int t = threadIdx.x;
    int own = (t < NBUK) ? T[t] : 0;
    s[t] = own;
    __syncthreads();
    for (int d = 1; d < 512; d <<= 1) {
        int add = (t >= d) ? s[t - d] : 0;
        __syncthreads();
        s[t] += add;
        __syncthreads();
    }
    if (t < NBUK) S[t] = s[t] - own;
    if (t == 511) S[NBUK] = s[511];
    if (t == 0) start[N] = E;
}

// ---- Phase C: LDS-staged bucket placement -> coalesced run writes ----
__global__ __launch_bounds__(256) void pC(const int* __restrict__ row, const int* __restrict__ col,
                                          const int* __restrict__ M, const int* __restrict__ S,
                                          unsigned int* __restrict__ ebuf, int E, int CH, int NBUK) {
    __shared__ unsigned int se[MAXCH];        // chunk edges, bucket-ordered
    __shared__ unsigned short pk[MAXCH];      // bucket id per LDS slot
    __shared__ int lhist[256], lbase[256], lcur[256], gbase[256];
    const int t = threadIdx.x, b = blockIdx.x;
    lhist[t] = 0;
    __syncthreads();
    const int s = b * CH, e = min(E, s + CH);
    const int cnt = e - s;
    const int n4 = cnt >> 2;
    const int4* c4 = (const int4*)(col + s);
    const int4* r4 = (const int4*)(row + s);
    for (int i = t; i < n4; i += 256) {
        int4 c = c4[i];
        atomicAdd(&lhist[c.x >> BSH], 1);
        atomicAdd(&lhist[c.y >> BSH], 1);
        atomicAdd(&lhist[c.z >> BSH], 1);
        atomicAdd(&lhist[c.w >> BSH], 1);
    }
    for (int i = (n4 << 2) + t; i < cnt; i += 256) atomicAdd(&lhist[col[s + i] >> BSH], 1);
    __syncthreads();
    {   // 256-wide exclusive scan of lhist -> lbase (scratch in lcur)
        int own = lhist[t];
        lcur[t] = own;
        __syncthreads();
        for (int d = 1; d < 256; d <<= 1) {
            int add = (t >= d) ? lcur[t - d] : 0;
            __syncthreads();
            lcur[t] += add;
            __syncthreads();
        }
        lbase[t] = lcur[t] - own;
        if (t < NBUK) gbase[t] = S[t] + M[b * NBUK + t] - lbase[t];
        lcur[t] = lbase[t];
    }
    __syncthreads();
    // placement into LDS (bucket-ordered)
    for (int i = t; i < n4; i += 256) {
        int4 c = c4[i];
        int4 r = r4[i];
        int k0 = c.x >> BSH, p0 = atomicAdd(&lcur[k0], 1);
        se[p0] = ((unsigned int)(c.x & (BSZ - 1)) << 17) | (unsigned int)r.x; pk[p0] = (unsigned short)k0;
        int k1 = c.y >> BSH, p1 = atomicAdd(&lcur[k1], 1);
        se[p1] = ((unsigned int)(c.y & (BSZ - 1)) << 17) | (unsigned int)r.y; pk[p1] = (unsigned short)k1;
        int k2 = c.z >> BSH, p2 = atomicAdd(&lcur[k2], 1);
        se[p2] = ((unsigned int)(c.z & (BSZ - 1)) << 17) | (unsigned int)r.z; pk[p2] = (unsigned short)k2;
        int k3 = c.w >> BSH, p3 = atomicAdd(&lcur[k3], 1);
        se[p3] = ((unsigned int)(c.w & (BSZ - 1)) << 17) | (unsigned int)r.w; pk[p3] = (unsigned short)k3;
    }
    for (int i = (n4 << 2) + t; i < cnt; i += 256) {
        int c = col[s + i], r = row[s + i];
        int k = c >> BSH, p = atomicAdd(&lcur[k], 1);
        se[p] = ((unsigned int)(c & (BSZ - 1)) << 17) | (unsigned int)r; pk[p] = (unsigned short)k;
    }
    __syncthreads();
    // coalesced write-out: consecutive LDS slots in a bucket -> consecutive global
    for (int i = t; i < cnt; i += 256) {
        int k = pk[i];
        ebuf[gbase[k] + i] = se[i];
    }
}

// ---- Phase C2: in-bucket counting sort by local col; emits dinv and CSR start ----
__global__ __launch_bounds__(512) void pC2(const unsigned int* __restrict__ ebuf,
                                           const int* __restrict__ S,
                                           unsigned int* __restrict__ ebuf2,
                                           float* __restrict__ dinv,
                                           int* __restrict__ start, int N) {
    __shared__ int h[BSZ], sc[BSZ], cur[BSZ];
    const int t = threadIdx.x, k = blockIdx.x;
    h[t] = 0;
    __syncthreads();
    const int s = S[k], e = S[k + 1];
    for (int i = s + t; i < e; i += 512) atomicAdd(&h[ebuf[i] >> 17], 1);
    __syncthreads();
    sc[t] = h[t];
    __syncthreads();
    for (int d = 1; d < 512; d <<= 1) {
        int add = (t >= d) ? sc[t - d] : 0;
        __syncthreads();
        sc[t] += add;
        __syncthreads();
    }
    cur[t] = sc[t] - h[t];             // exclusive scan
    const int v = (k << BSH) + t;
    if (v < N) {
        dinv[v] = rsqrtf((float)h[t] + 1.0f);
        start[v] = s + cur[t];
    }
    __syncthreads();
    for (int i = s + t; i < e; i += 512) {
        unsigned int w = ebuf[i];
        int p = atomicAdd(&cur[w >> 17], 1);
        ebuf2[s + p] = w;
    }
}

// ---- GEMM1: ts1h[v] = half((x[v] @ W1) * dinv[v]) ----
__global__ __launch_bounds__(256) void k_gemm1(
    const float* __restrict__ x, const float* __restrict__ W1,
    const float* __restrict__ dinv, __half* __restrict__ ts, int N) {
    __shared__ float wsT[16 * 132];
    const int tid = threadIdx.x;
    for (int idx = tid; idx < 2048; idx += 256) {
        int k = idx >> 4, c = idx & 15;
        wsT[c * 132 + k] = W1[idx];
    }
    __syncthreads();
    const int n = blockIdx.x * 256 + tid;
    if (n >= N) return;
    const float4* xr = (const float4*)(x + (size_t)n * 128);
    float acc[16];
    #pragma unroll
    for (int c = 0; c < 16; ++c) acc[c] = 0.f;
    #pragma unroll 4
    for (int k4 = 0; k4 < 32; ++k4) {
        float4 a = xr[k4];
        #pragma unroll
        for (int c = 0; c < 16; ++c) {
            const float4 w = *(const float4*)&wsT[c * 132 + k4 * 4];
            acc[c] = fmaf(a.x, w.x, fmaf(a.y, w.y, fmaf(a.z, w.z, fmaf(a.w, w.w, acc[c]))));
        }
    }
    float dv = dinv[n];
    union { __half h[16]; uint4 u[2]; } o;
    #pragma unroll
    for (int c = 0; c < 16; ++c) o.h[c] = __float2half(acc[c] * dv);
    uint4* dst = (uint4*)(ts + (size_t)n * 16);
    dst[0] = o.u[0]; dst[1] = o.u[1];
}

// ---- Layer-1 aggregation: 8 lanes/node (lane = channel pair), CSR gather,
//      fused bias/ReLU + 16x16 W2 via width-8 shuffles (R8-proven form) ----
__global__ __launch_bounds__(256) void pGat1(
    const unsigned int* __restrict__ ebuf2, const int* __restrict__ start,
    const __half2* __restrict__ tsv, const float* __restrict__ dinv,
    const float* __restrict__ b1, const float* __restrict__ W2,
    __half2* __restrict__ ts2v, int N) {
    __shared__ float w2s[256];
    const int tid = threadIdx.x;
    w2s[tid] = W2[tid];
    __syncthreads();
    const int l = tid & 7;                 // channel pair: c0=2l, c1=2l+1
    const int v = blockIdx.x * 32 + (tid >> 3);
    if (v >= N) return;
    const int s = start[v], e = start[v + 1];
    float sx = 0.f, sy = 0.f;
    int i = s;
    for (; i + 4 <= e; i += 4) {
        int r0 = ebuf2[i]     & 0x1FFFF;
        int r1 = ebuf2[i + 1] & 0x1FFFF;
        int r2 = ebuf2[i + 2] & 0x1FFFF;
        int r3 = ebuf2[i + 3] & 0x1FFFF;
        float2 f0 = __half22float2(tsv[(size_t)r0 * 8 + l]);
        float2 f1 = __half22float2(tsv[(size_t)r1 * 8 + l]);
        float2 f2 = __half22float2(tsv[(size_t)r2 * 8 + l]);
        float2 f3 = __half22float2(tsv[(size_t)r3 * 8 + l]);
        sx += (f0.x + f1.x) + (f2.x + f3.x);
        sy += (f0.y + f1.y) + (f2.y + f3.y);
    }
    for (; i < e; ++i) {
        int r = ebuf2[i] & 0x1FFFF;
        float2 f = __half22float2(tsv[(size_t)r * 8 + l]);
        sx += f.x; sy += f.y;
    }
    const float dv = dinv[v];
    float2 sf = __half22float2(tsv[(size_t)v * 8 + l]);
    float hx = fmaxf(dv * (sx + sf.x) + b1[2 * l],     0.f);
    float hy = fmaxf(dv * (sy + sf.y) + b1[2 * l + 1], 0.f);
    float ox = 0.f, oy = 0.f;
    #pragma unroll
    for (int j = 0; j < 8; ++j) {
        float ax = __shfl(hx, j, 8);       // channel 2j
        float ay = __shfl(hy, j, 8);       // channel 2j+1
        ox = fmaf(ax, w2s[(2 * j) * 16 + 2 * l],     fmaf(ay, w2s[(2 * j + 1) * 16 + 2 * l],     ox));
        oy = fmaf(ax, w2s[(2 * j) * 16 + 2 * l + 1], fmaf(ay, w2s[(2 * j + 1) * 16 + 2 * l + 1], oy));
    }
    ts2v[(size_t)v * 8 + l] = __halves2half2(__float2half(dv * ox), __float2half(dv * oy));
}

// ---- Layer-2 aggregation: 8 lanes/node CSR gather + final bias -> h2 ----
__global__ __launch_bounds__(256) void pGat2(
    const unsigned int* __restrict__ ebuf2, const int* __restrict__ start,
    const __half2* __restrict__ tsv, const float* __restrict__ dinv,
    const float* __restrict__ b2, __half2* __restrict__ h2v, int N) {
    const int tid = threadIdx.x;
    const int l = tid & 7;
    const int v = blockIdx.x * 32 + (tid >> 3);
    if (v >= N) return;
    const int s = start[v], e = start[v + 1];
    float sx = 0.f, sy = 0.f;
    int i = s;
    for (; i + 4 <= e; i += 4) {
        int r0 = ebuf2[i]     & 0x1FFFF;
        int r1 = ebuf2[i + 1] & 0x1FFFF;
        int r2 = ebuf2[i + 2] & 0x1FFFF;
        int r3 = ebuf2[i + 3] & 0x1FFFF;
        float2 f0 = __half22float2(tsv[(size_t)r0 * 8 + l]);
        float2 f1 = __half22float2(tsv[(size_t)r1 * 8 + l]);
        float2 f2 = __half22float2(tsv[(size_t)r2 * 8 + l]);
        float2 f3 = __half22float2(tsv[(size_t)r3 * 8 + l]);
        sx += (f0.x + f1.x) + (f2.x + f3.x);
        sy += (f0.y + f1.y) + (f2.y + f3.y);
    }
    for (; i < e; ++i) {
        int r = ebuf2[i] & 0x1FFFF;
        float2 f = __half22float2(tsv[(size_t)r * 8 + l]);
        sx += f.x; sy += f.y;
    }
    float2 sf = __half22float2(tsv[(size_t)v * 8 + l]);
    const float dv = dinv[v];
    h2v[(size_t)v * 8 + l] = __halves2half2(
        __float2half(dv * (sx + sf.x) + b2[2 * l]),
        __float2half(dv * (sy + sf.y) + b2[2 * l + 1]));
}

// ---- Edge scores (R8-proven: 1 edge/thread) ----
__global__ void k_score(const int* __restrict__ row, const int* __restrict__ col,
                        const __half* __restrict__ h2h, float* __restrict__ out, int E) {
    int e = blockIdx.x * 256 + threadIdx.x;
    if (e < E) {
        union { uint4 u[2]; __half2 h[8]; } a, b;
        const uint4* pa = (const uint4*)(h2h + (size_t)row[e] * 16);
        const uint4* pb = (const uint4*)(h2h + (size_t)col[e] * 16);
        a.u[0] = pa[0]; a.u[1] = pa[1];
        b.u[0] = pb[0]; b.u[1] = pb[1];
        float d = 0.f;
        #pragma unroll
        for (int i = 0; i < 8; ++i) {
            float2 fa = __half22float2(a.h[i]);
            float2 fb = __half22float2(b.h[i]);
            d = fmaf(fa.x, fb.x, fmaf(fa.y, fb.y, d));
        }
        out[e] = 1.0f / (1.0f + __expf(-d));
    }
}

// ---------------- Fallback (R2 atomic path) ----------------
__global__ void k_countf(const int* __restrict__ col, float* __restrict__ deg, int E) {
    int e = blockIdx.x * 256 + threadIdx.x;
    if (e < E) atomicAdd(&deg[col[e]], 1.0f);
}
__global__ void k_dinvf(float* __restrict__ dinv, int N) {
    int v = blockIdx.x * 256 + threadIdx.x;
    if (v < N) dinv[v] = rsqrtf(dinv[v] + 1.0f);
}
__global__ __launch_bounds__(256) void k_gemm1f(
    const float* __restrict__ x, const float* __restrict__ W1,
    const float* __restrict__ dinv, float* __restrict__ ts, int N) {
    __shared__ float wsT[16 * 132];
    const int tid = threadIdx.x;
    for (int idx = tid; idx < 2048; idx += 256) {
        int k = idx >> 4, c = idx & 15;
        wsT[c * 132 + k] = W1[idx];
    }
    __syncthreads();
    const int n = blockIdx.x * 256 + tid;
    if (n >= N) return;
    const float4* xr = (const float4*)(x + (size_t)n * 128);
    float acc[16];
    #pragma unroll
    for (int c = 0; c < 16; ++c) acc[c] = 0.f;
    for (int k4 = 0; k4 < 32; ++k4) {
        float4 a = xr[k4];
        #pragma unroll
        for (int c = 0; c < 16; ++c) {
            const float4 w = *(const float4*)&wsT[c * 132 + k4 * 4];
            acc[c] = fmaf(a.x, w.x, fmaf(a.y, w.y, fmaf(a.z, w.z, fmaf(a.w, w.w, acc[c]))));
        }
    }
    float dv = dinv[n];
    float4* o = (float4*)(ts + (size_t)n * 16);
    #pragma unroll
    for (int q = 0; q < 4; ++q)
        o[q] = make_float4(acc[4*q] * dv, acc[4*q+1] * dv, acc[4*q+2] * dv, acc[4*q+3] * dv);
}
__global__ void k_scatter(const int* __restrict__ row, const int* __restrict__ col,
                          const float* __restrict__ ts, float* __restrict__ acc, int E) {
    int g = blockIdx.x * 256 + threadIdx.x;
    int e = g >> 4, c = g & 15;
    if (e < E) atomicAdd(&acc[(size_t)col[e] * 16 + c], ts[(size_t)row[e] * 16 + c]);
}
__global__ void k_finalize(float* __restrict__ acc, const float* __restrict__ ts,
                           const float* __restrict__ dinv, const float* __restrict__ b,
                           int N, int relu) {
    int g = blockIdx.x * 256 + threadIdx.x;
    int v = g >> 4, c = g & 15;
    if (v < N) {
        float h = dinv[v] * (acc[g] + ts[g]) + b[c];
        if (relu) h = fmaxf(h, 0.f);
        acc[g] = h;
    }
}
__global__ __launch_bounds__(256) void k_gemm2f(
    const float* __restrict__ h1, const float* __restrict__ W2,
    const float* __restrict__ dinv, float* __restrict__ ts2, int N) {
    __shared__ float hs[16 * 17];
    __shared__ float ws2[256];
    const int tid = threadIdx.x;
    const int base = blockIdx.x * 16;
    if (tid < 64) ((float4*)ws2)[tid] = ((const float4*)W2)[tid];
    if (tid >= 64 && tid < 128) {
        int t2 = tid - 64;
        float4 v4 = ((const float4*)(h1 + (size_t)base * 16))[t2];
        float* d = &hs[(t2 >> 2) * 17 + (t2 & 3) * 4];
        d[0] = v4.x; d[1] = v4.y; d[2] = v4.z; d[3] = v4.w;
    }
    __syncthreads();
    const int r = tid >> 4, c = tid & 15;
    float a = 0.f;
    #pragma unroll
    for (int kk = 0; kk < 16; ++kk) a = fmaf(hs[r * 17 + kk], ws2[kk * 16 + c], a);
    ts2[(size_t)(base + r) * 16 + c] = a * dinv[base + r];
}
__global__ void k_scoref(const int* __restrict__ row, const int* __restrict__ col,
                         const float* __restrict__ h2, float* __restrict__ out, int E) {
    int e = blockIdx.x * 256 + threadIdx.x;
    if (e < E) {
        const float4* a = (const float4*)(h2 + (size_t)row[e] * 16);
        const float4* b = (const float4*)(h2 + (size_t)col[e] * 16);
        float d = 0.f;
        #pragma unroll
        for (int i = 0; i < 4; ++i) {
            float4 u = a[i], v = b[i];
            d += u.x * v.x + u.y * v.y + u.z * v.z + u.w * v.w;
        }
        out[e] = 1.0f / (1.0f + __expf(-d));
    }
}

extern "C" void kernel_launch(void* const* d_in, const int* in_sizes, int n_in,
                              void* d_out, int out_size, void* d_ws, size_t ws_size,
                              hipStream_t stream) {
    const float* x  = (const float*)d_in[0];
    const int*   ei = (const int*)d_in[1];
    const float* W1 = (const float*)d_in[2];
    const float* b1 = (const float*)d_in[3];
    const float* W2 = (const float*)d_in[4];
    const float* b2 = (const float*)d_in[5];

    const int N = in_sizes[0] / 128;   // 100000
    const int E = in_sizes[1] / 2;     // 3200000
    const int* row = ei;
    const int* col = ei + E;
    float* out = (float*)d_out;

    const int NBUK = (N + BSZ - 1) / BSZ;          // 196
    const int CN = (E + MAXCH - 1) / MAXCH;        // 1000 chunks
    const int CH = MAXCH;                          // 3200, multiple of 4

    char* ws = (char*)d_ws;
    size_t off = 0;
    auto alloc = [&](size_t bytes) { void* p = ws + off; off += (bytes + 255) & ~(size_t)255; return p; };
    float*  dinv  = (float*)alloc((size_t)N * 4);
    __half* ts1h  = (__half*)alloc((size_t)N * 32);    // also h2h after pGat1
    __half* ts2h  = (__half*)alloc((size_t)N * 32);
    int*    start = (int*)alloc((size_t)(N + 1) * 4);
    int*    M     = (int*)alloc((size_t)CN * NBUK * 4);
    int*    T     = (int*)alloc((size_t)NBUK * 4);
    int*    S     = (int*)alloc((size_t)(NBUK + 1) * 4);
    unsigned int* ebuf  = (unsigned int*)alloc((size_t)E * 4);
    unsigned int* ebuf2 = (unsigned int*)alloc((size_t)E * 4);
    const size_t need = off;    // ~34 MB at N=100k, E=3.2M

    if (N <= 131072 && NBUK <= 256 && CN <= MAXCHUNKS && ws_size >= need) {
        pA <<<CN, 256, 0, stream>>>(col, M, E, CH, NBUK);
        pB1<<<NBUK, 1024, 0, stream>>>(M, T, NBUK, CN);
        pB2<<<1, 512, 0, stream>>>(T, S, start, NBUK, N, E);
        pC <<<CN, 256, 0, stream>>>(row, col, M, S, ebuf, E, CH, NBUK);
        pC2<<<NBUK, 512, 0, stream>>>(ebuf, S, ebuf2, dinv, start, N);
        k_gemm1<<<(N + 255) / 256, 256, 0, stream>>>(x, W1, dinv, ts1h, N);
        pGat1<<<(N + 31) / 32, 256, 0, stream>>>(ebuf2, start, (const __half2*)ts1h, dinv, b1, W2,
                                                 (__half2*)ts2h, N);
        __half* h2h = ts1h;   // ts1h dead after pGat1
        pGat2<<<(N + 31) / 32, 256, 0, stream>>>(ebuf2, start, (const __half2*)ts2h, dinv, b2,
                                                 (__half2*)h2h, N);
        k_score<<<(E + 255) / 256, 256, 0, stream>>>(row, col, h2h, out, E);
    } else {
        // R2 fallback, fp32 buffers carved independently
        float* dinvF = (float*)ws;
        float* ts1F  = (float*)(ws + (size_t)N * 4);
        float* ts2F  = (float*)(ws + (size_t)N * 4 + (size_t)N * 64);
        hipMemsetAsync(dinvF, 0, (size_t)N * 4, stream);
        hipMemsetAsync(ts2F, 0, (size_t)N * 64, stream);
        k_countf<<<(E + 255) / 256, 256, 0, stream>>>(col, dinvF, E);
        k_dinvf<<<(N + 255) / 256, 256, 0, stream>>>(dinvF, N);
        k_gemm1f<<<(N + 255) / 256, 256, 0, stream>>>(x, W1, dinvF, ts1F, N);
        k_scatter<<<(E * 16) / 256, 256, 0, stream>>>(row, col, ts1F, ts2F, E);
        k_finalize<<<(N * 16 + 255) / 256, 256, 0, stream>>>(ts2F, ts1F, dinvF, b1, N, 1);
        k_gemm2f<<<N / 16, 256, 0, stream>>>(ts2F, W2, dinvF, ts1F, N);
        hipMemsetAsync(ts2F, 0, (size_t)N * 64, stream);
        k_scatter<<<(E * 16) / 256, 256, 0, stream>>>(row, col, ts1F, ts2F, E);
        k_finalize<<<(N * 16 + 255) / 256, 256, 0, stream>>>(ts2F, ts1F, dinvF, b2, N, 0);
        k_scoref<<<(E + 255) / 256, 256, 0, stream>>>(row, col, ts2F, out, E);
    }
}

// Round 11
// 251.447 us; speedup vs baseline: 1.2027x; 1.0544x over previous
//
#include <hip/hip_runtime.h>
#include <hip/hip_bf16.h>
#include <hip/hip_fp16.h>
#include <math.h>

// GCN link prediction. R11 = R10 structure (LDS-staged counting sort by dest
// col + CSR gather aggregation) with: 8-deep unrolled gather loops (NO
// nontemporal hints -- R9 showed NT on ebuf2 defeats its L2 reuse between
// pGat1/pGat2), and wider blocks in the sort phases (pA/pC 512 thr, pC2 1024
// thr) to halve serial per-block loop lengths.
//   deg[v] = incount(col==v)+1 ; dinv = rsqrt(deg)
//   ts[v]  = (h[v]@W)*dinv[v]          (fp16 gather tables, L2-resident)
//   h'[c]  = act(dinv[c]*(sum_{e:col=c} ts[row_e] + ts[c]) + b)
//   score  = sigmoid(dot(h2[row], h2[col]))

#define BSH 9
#define BSZ 512            // nodes per bucket -> NBUK = 196 (<= 256)
#define MAXCH 3200         // edges per chunk (multiple of 4)
#define MAXCHUNKS 1024

// ---- Phase A: per-(chunk,bucket) histogram -> M[b][NBUK] ----
__global__ __launch_bounds__(512) void pA(const int* __restrict__ col,
                                          int* __restrict__ M, int E, int CH, int NBUK) {
    __shared__ int hist[256];
    const int t = threadIdx.x, b = blockIdx.x;
    if (t < 256) hist[t] = 0;
    __syncthreads();
    const int s = b * CH, e = min(E, s + CH);
    const int n4 = (e - s) >> 2;                 // CH % 4 == 0 -> 16B-aligned
    const int4* c4 = (const int4*)(col + s);
    for (int i = t; i < n4; i += 512) {
        int4 c = c4[i];
        atomicAdd(&hist[c.x >> BSH], 1);
        atomicAdd(&hist[c.y >> BSH], 1);
        atomicAdd(&hist[c.z >> BSH], 1);
        atomicAdd(&hist[c.w >> BSH], 1);
    }
    for (int i = s + (n4 << 2) + t; i < e; i += 512) atomicAdd(&hist[col[i] >> BSH], 1);
    __syncthreads();
    for (int i = t; i < NBUK; i += 512) M[b * NBUK + i] = hist[i];
}

// ---- Phase B1: per-bucket exclusive scan over CN chunks (CN <= 1024) ----
__global__ __launch_bounds__(1024) void pB1(int* __restrict__ M, int* __restrict__ T,
                                            int NBUK, int CN) {
    __shared__ int s[1024];
    const int t = threadIdx.x, k = blockIdx.x;
    int own = (t < CN) ? M[t * NBUK + k] : 0;
    s[t] = own;
    __syncthreads();
    for (int d = 1; d < 1024; d <<= 1) {
        int add = (t >= d) ? s[t - d] : 0;
        __syncthreads();
        s[t] += add;
        __syncthreads();
    }
    if (t < CN) M[t * NBUK + k] = s[t] - own;
    if (t == 1023) T[k] = s[1023];
}

// ---- Phase B2: exclusive scan of bucket totals -> S[0..NBUK]; also start[N]=E ----
__global__ __launch_bounds__(512) void pB2(const int* __restrict__ T, int* __restrict__ S,
                                           int* __restrict__ start, int NBUK, int N, int E) {
    __shared__ int s[512];
    const int t = threadIdx.x;
    int own = (t < NBUK) ? T[t] : 0;
    s[t] = own;
    __syncthreads();
    for (int d = 1; d < 512; d <<= 1) {
        int add = (t >= d) ? s[t - d] : 0;
        __syncthreads();
        s[t] += add;
        __syncthreads();
    }
    if (t < NBUK) S[t] = s[t] - own;
    if (t == 511) S[NBUK] = s[511];
    if (t == 0) start[N] = E;
}

// ---- Phase C: LDS-staged bucket placement -> coalesced run writes ----
__global__ __launch_bounds__(512) void pC(const int* __restrict__ row, const int* __restrict__ col,
                                          const int* __restrict__ M, const int* __restrict__ S,
                                          unsigned int* __restrict__ ebuf, int E, int CH, int NBUK) {
    __shared__ unsigned int se[MAXCH];        // chunk edges, bucket-ordered
    __shared__ unsigned short pk[MAXCH];      // bucket id per LDS slot
    __shared__ int lhist[256], lbase[256], lcur[256], gbase[256];
    const int t = threadIdx.x, b = blockIdx.x;
    if (t < 256) lhist[t] = 0;
    __syncthreads();
    const int s = b * CH, e = min(E, s + CH);
    const int cnt = e - s;
    const int n4 = cnt >> 2;
    const int4* c4 = (const int4*)(col + s);
    const int4* r4 = (const int4*)(row + s);
    for (int i = t; i < n4; i += 512) {
        int4 c = c4[i];
        atomicAdd(&lhist[c.x >> BSH], 1);
        atomicAdd(&lhist[c.y >> BSH], 1);
        atomicAdd(&lhist[c.z >> BSH], 1);
        atomicAdd(&lhist[c.w >> BSH], 1);
    }
    for (int i = (n4 << 2) + t; i < cnt; i += 512) atomicAdd(&lhist[col[s + i] >> BSH], 1);
    __syncthreads();
    {   // 256-wide exclusive scan of lhist -> lbase (scratch in lcur); threads 0-255
        int own = (t < 256) ? lhist[t] : 0;
        if (t < 256) lcur[t] = own;
        __syncthreads();
        for (int d = 1; d < 256; d <<= 1) {
            int add = (t < 256 && t >= d) ? lcur[t - d] : 0;
            __syncthreads();
            if (t < 256) lcur[t] += add;
            __syncthreads();
        }
        if (t < 256) {
            lbase[t] = lcur[t] - own;
            lcur[t] = lcur[t] - own;
        }
        __syncthreads();
        if (t < NBUK) gbase[t] = S[t] + M[b * NBUK + t] - lbase[t];
    }
    __syncthreads();
    // placement into LDS (bucket-ordered)
    for (int i = t; i < n4; i += 512) {
        int4 c = c4[i];
        int4 r = r4[i];
        int k0 = c.x >> BSH, p0 = atomicAdd(&lcur[k0], 1);
        se[p0] = ((unsigned int)(c.x & (BSZ - 1)) << 17) | (unsigned int)r.x; pk[p0] = (unsigned short)k0;
        int k1 = c.y >> BSH, p1 = atomicAdd(&lcur[k1], 1);
        se[p1] = ((unsigned int)(c.y & (BSZ - 1)) << 17) | (unsigned int)r.y; pk[p1] = (unsigned short)k1;
        int k2 = c.z >> BSH, p2 = atomicAdd(&lcur[k2], 1);
        se[p2] = ((unsigned int)(c.z & (BSZ - 1)) << 17) | (unsigned int)r.z; pk[p2] = (unsigned short)k2;
        int k3 = c.w >> BSH, p3 = atomicAdd(&lcur[k3], 1);
        se[p3] = ((unsigned int)(c.w & (BSZ - 1)) << 17) | (unsigned int)r.w; pk[p3] = (unsigned short)k3;
    }
    for (int i = (n4 << 2) + t; i < cnt; i += 512) {
        int c = col[s + i], r = row[s + i];
        int k = c >> BSH, p = atomicAdd(&lcur[k], 1);
        se[p] = ((unsigned int)(c & (BSZ - 1)) << 17) | (unsigned int)r; pk[p] = (unsigned short)k;
    }
    __syncthreads();
    // coalesced write-out: consecutive LDS slots in a bucket -> consecutive global
    for (int i = t; i < cnt; i += 512) {
        int k = pk[i];
        ebuf[gbase[k] + i] = se[i];
    }
}

// ---- Phase C2: in-bucket counting sort by local col; emits dinv and CSR start ----
__global__ __launch_bounds__(1024) void pC2(const unsigned int* __restrict__ ebuf,
                                            const int* __restrict__ S,
                                            unsigned int* __restrict__ ebuf2,
                                            float* __restrict__ dinv,
                                            int* __restrict__ start, int N) {
    __shared__ int h[BSZ], sc[BSZ], cur[BSZ];
    const int t = threadIdx.x, k = blockIdx.x;
    if (t < BSZ) h[t] = 0;
    __syncthreads();
    const int s = S[k], e = S[k + 1];
    for (int i = s + t; i < e; i += 1024) atomicAdd(&h[ebuf[i] >> 17], 1);
    __syncthreads();
    if (t < BSZ) sc[t] = h[t];
    __syncthreads();
    for (int d = 1; d < BSZ; d <<= 1) {
        int add = (t < BSZ && t >= d) ? sc[t - d] : 0;
        __syncthreads();
        if (t < BSZ) sc[t] += add;
        __syncthreads();
    }
    if (t < BSZ) {
        cur[t] = sc[t] - h[t];             // exclusive scan
        const int v = (k << BSH) + t;
        if (v < N) {
            dinv[v] = rsqrtf((float)h[t] + 1.0f);
            start[v] = s + cur[t];
        }
    }
    __syncthreads();
    for (int i = s + t; i < e; i += 1024) {
        unsigned int w = ebuf[i];
        int p = atomicAdd(&cur[w >> 17], 1);
        ebuf2[s + p] = w;
    }
}

// ---- GEMM1: ts1h[v] = half((x[v] @ W1) * dinv[v]) ----
__global__ __launch_bounds__(256) void k_gemm1(
    const float* __restrict__ x, const float* __restrict__ W1,
    const float* __restrict__ dinv, __half* __restrict__ ts, int N) {
    __shared__ float wsT[16 * 132];
    const int tid = threadIdx.x;
    for (int idx = tid; idx < 2048; idx += 256) {
        int k = idx >> 4, c = idx & 15;
        wsT[c * 132 + k] = W1[idx];
    }
    __syncthreads();
    const int n = blockIdx.x * 256 + tid;
    if (n >= N) return;
    const float4* xr = (const float4*)(x + (size_t)n * 128);
    float acc[16];
    #pragma unroll
    for (int c = 0; c < 16; ++c) acc[c] = 0.f;
    #pragma unroll 4
    for (int k4 = 0; k4 < 32; ++k4) {
        float4 a = xr[k4];
        #pragma unroll
        for (int c = 0; c < 16; ++c) {
            const float4 w = *(const float4*)&wsT[c * 132 + k4 * 4];
            acc[c] = fmaf(a.x, w.x, fmaf(a.y, w.y, fmaf(a.z, w.z, fmaf(a.w, w.w, acc[c]))));
        }
    }
    float dv = dinv[n];
    union { __half h[16]; uint4 u[2]; } o;
    #pragma unroll
    for (int c = 0; c < 16; ++c) o.h[c] = __float2half(acc[c] * dv);
    uint4* dst = (uint4*)(ts + (size_t)n * 16);
    dst[0] = o.u[0]; dst[1] = o.u[1];
}

// ---- Layer-1 aggregation: 8 lanes/node, 8-deep unrolled CSR gather (no NT),
//      fused bias/ReLU + 16x16 W2 via width-8 shuffles ----
__global__ __launch_bounds__(256) void pGat1(
    const unsigned int* __restrict__ ebuf2, const int* __restrict__ start,
    const __half2* __restrict__ tsv, const float* __restrict__ dinv,
    const float* __restrict__ b1, const float* __restrict__ W2,
    __half2* __restrict__ ts2v, int N) {
    __shared__ float w2s[256];
    const int tid = threadIdx.x;
    w2s[tid] = W2[tid];
    __syncthreads();
    const int l = tid & 7;                 // channel pair: c0=2l, c1=2l+1
    const int v = blockIdx.x * 32 + (tid >> 3);
    if (v >= N) return;
    const int s = start[v], e = start[v + 1];
    float sx = 0.f, sy = 0.f;
    int i = s;
    for (; i + 8 <= e; i += 8) {
        unsigned int w0 = ebuf2[i],     w1 = ebuf2[i + 1];
        unsigned int w2 = ebuf2[i + 2], w3 = ebuf2[i + 3];
        unsigned int w4 = ebuf2[i + 4], w5 = ebuf2[i + 5];
        unsigned int w6 = ebuf2[i + 6], w7 = ebuf2[i + 7];
        float2 f0 = __half22float2(tsv[(size_t)(w0 & 0x1FFFF) * 8 + l]);
        float2 f1 = __half22float2(tsv[(size_t)(w1 & 0x1FFFF) * 8 + l]);
        float2 f2 = __half22float2(tsv[(size_t)(w2 & 0x1FFFF) * 8 + l]);
        float2 f3 = __half22float2(tsv[(size_t)(w3 & 0x1FFFF) * 8 + l]);
        float2 f4 = __half22float2(tsv[(size_t)(w4 & 0x1FFFF) * 8 + l]);
        float2 f5 = __half22float2(tsv[(size_t)(w5 & 0x1FFFF) * 8 + l]);
        float2 f6 = __half22float2(tsv[(size_t)(w6 & 0x1FFFF) * 8 + l]);
        float2 f7 = __half22float2(tsv[(size_t)(w7 & 0x1FFFF) * 8 + l]);
        sx += ((f0.x + f1.x) + (f2.x + f3.x)) + ((f4.x + f5.x) + (f6.x + f7.x));
        sy += ((f0.y + f1.y) + (f2.y + f3.y)) + ((f4.y + f5.y) + (f6.y + f7.y));
    }
    for (; i + 4 <= e; i += 4) {
        unsigned int w0 = ebuf2[i],     w1 = ebuf2[i + 1];
        unsigned int w2 = ebuf2[i + 2], w3 = ebuf2[i + 3];
        float2 f0 = __half22float2(tsv[(size_t)(w0 & 0x1FFFF) * 8 + l]);
        float2 f1 = __half22float2(tsv[(size_t)(w1 & 0x1FFFF) * 8 + l]);
        float2 f2 = __half22float2(tsv[(size_t)(w2 & 0x1FFFF) * 8 + l]);
        float2 f3 = __half22float2(tsv[(size_t)(w3 & 0x1FFFF) * 8 + l]);
        sx += (f0.x + f1.x) + (f2.x + f3.x);
        sy += (f0.y + f1.y) + (f2.y + f3.y);
    }
    for (; i < e; ++i) {
        unsigned int w = ebuf2[i];
        float2 f = __half22float2(tsv[(size_t)(w & 0x1FFFF) * 8 + l]);
        sx += f.x; sy += f.y;
    }
    const float dv = dinv[v];
    float2 sf = __half22float2(tsv[(size_t)v * 8 + l]);
    float hx = fmaxf(dv * (sx + sf.x) + b1[2 * l],     0.f);
    float hy = fmaxf(dv * (sy + sf.y) + b1[2 * l + 1], 0.f);
    float ox = 0.f, oy = 0.f;
    #pragma unroll
    for (int j = 0; j < 8; ++j) {
        float ax = __shfl(hx, j, 8);       // channel 2j
        float ay = __shfl(hy, j, 8);       // channel 2j+1
        ox = fmaf(ax, w2s[(2 * j) * 16 + 2 * l],     fmaf(ay, w2s[(2 * j + 1) * 16 + 2 * l],     ox));
        oy = fmaf(ax, w2s[(2 * j) * 16 + 2 * l + 1], fmaf(ay, w2s[(2 * j + 1) * 16 + 2 * l + 1], oy));
    }
    ts2v[(size_t)v * 8 + l] = __halves2half2(__float2half(dv * ox), __float2half(dv * oy));
}

// ---- Layer-2 aggregation: 8 lanes/node, 8-deep unrolled CSR gather + bias ----
__global__ __launch_bounds__(256) void pGat2(
    const unsigned int* __restrict__ ebuf2, const int* __restrict__ start,
    const __half2* __restrict__ tsv, const float* __restrict__ dinv,
    const float* __restrict__ b2, __half2* __restrict__ h2v, int N) {
    const int tid = threadIdx.x;
    const int l = tid & 7;
    const int v = blockIdx.x * 32 + (tid >> 3);
    if (v >= N) return;
    const int s = start[v], e = start[v + 1];
    float sx = 0.f, sy = 0.f;
    int i = s;
    for (; i + 8 <= e; i += 8) {
        unsigned int w0 = ebuf2[i],     w1 = ebuf2[i + 1];
        unsigned int w2 = ebuf2[i + 2], w3 = ebuf2[i + 3];
        unsigned int w4 = ebuf2[i + 4], w5 = ebuf2[i + 5];
        unsigned int w6 = ebuf2[i + 6], w7 = ebuf2[i + 7];
        float2 f0 = __half22float2(tsv[(size_t)(w0 & 0x1FFFF) * 8 + l]);
        float2 f1 = __half22float2(tsv[(size_t)(w1 & 0x1FFFF) * 8 + l]);
        float2 f2 = __half22float2(tsv[(size_t)(w2 & 0x1FFFF) * 8 + l]);
        float2 f3 = __half22float2(tsv[(size_t)(w3 & 0x1FFFF) * 8 + l]);
        float2 f4 = __half22float2(tsv[(size_t)(w4 & 0x1FFFF) * 8 + l]);
        float2 f5 = __half22float2(tsv[(size_t)(w5 & 0x1FFFF) * 8 + l]);
        float2 f6 = __half22float2(tsv[(size_t)(w6 & 0x1FFFF) * 8 + l]);
        float2 f7 = __half22float2(tsv[(size_t)(w7 & 0x1FFFF) * 8 + l]);
        sx += ((f0.x + f1.x) + (f2.x + f3.x)) + ((f4.x + f5.x) + (f6.x + f7.x));
        sy += ((f0.y + f1.y) + (f2.y + f3.y)) + ((f4.y + f5.y) + (f6.y + f7.y));
    }
    for (; i + 4 <= e; i += 4) {
        unsigned int w0 = ebuf2[i],     w1 = ebuf2[i + 1];
        unsigned int w2 = ebuf2[i + 2], w3 = ebuf2[i + 3];
        float2 f0 = __half22float2(tsv[(size_t)(w0 & 0x1FFFF) * 8 + l]);
        float2 f1 = __half22float2(tsv[(size_t)(w1 & 0x1FFFF) * 8 + l]);
        float2 f2 = __half22float2(tsv[(size_t)(w2 & 0x1FFFF) * 8 + l]);
        float2 f3 = __half22float2(tsv[(size_t)(w3 & 0x1FFFF) * 8 + l]);
        sx += (f0.x + f1.x) + (f2.x + f3.x);
        sy += (f0.y + f1.y) + (f2.y + f3.y);
    }
    for (; i < e; ++i) {
        unsigned int w = ebuf2[i];
        float2 f = __half22float2(tsv[(size_t)(w & 0x1FFFF) * 8 + l]);
        sx += f.x; sy += f.y;
    }
    float2 sf = __half22float2(tsv[(size_t)v * 8 + l]);
    const float dv = dinv[v];
    h2v[(size_t)v * 8 + l] = __halves2half2(
        __float2half(dv * (sx + sf.x) + b2[2 * l]),
        __float2half(dv * (sy + sf.y) + b2[2 * l + 1]));
}

// ---- Edge scores (R8/R10-proven: 1 edge/thread, no NT) ----
__global__ void k_score(const int* __restrict__ row, const int* __restrict__ col,
                        const __half* __restrict__ h2h, float* __restrict__ out, int E) {
    int e = blockIdx.x * 256 + threadIdx.x;
    if (e < E) {
        union { uint4 u[2]; __half2 h[8]; } a, b;
        const uint4* pa = (const uint4*)(h2h + (size_t)row[e] * 16);
        const uint4* pb = (const uint4*)(h2h + (size_t)col[e] * 16);
        a.u[0] = pa[0]; a.u[1] = pa[1];
        b.u[0] = pb[0]; b.u[1] = pb[1];
        float d = 0.f;
        #pragma unroll
        for (int i = 0; i < 8; ++i) {
            float2 fa = __half22float2(a.h[i]);
            float2 fb = __half22float2(b.h[i]);
            d = fmaf(fa.x, fb.x, fmaf(fa.y, fb.y, d));
        }
        out[e] = 1.0f / (1.0f + __expf(-d));
    }
}

// ---------------- Fallback (R2 atomic path) ----------------
__global__ void k_countf(const int* __restrict__ col, float* __restrict__ deg, int E) {
    int e = blockIdx.x * 256 + threadIdx.x;
    if (e < E) atomicAdd(&deg[col[e]], 1.0f);
}
__global__ void k_dinvf(float* __restrict__ dinv, int N) {
    int v = blockIdx.x * 256 + threadIdx.x;
    if (v < N) dinv[v] = rsqrtf(dinv[v] + 1.0f);
}
__global__ __launch_bounds__(256) void k_gemm1f(
    const float* __restrict__ x, const float* __restrict__ W1,
    const float* __restrict__ dinv, float* __restrict__ ts, int N) {
    __shared__ float wsT[16 * 132];
    const int tid = threadIdx.x;
    for (int idx = tid; idx < 2048; idx += 256) {
        int k = idx >> 4, c = idx & 15;
        wsT[c * 132 + k] = W1[idx];
    }
    __syncthreads();
    const int n = blockIdx.x * 256 + tid;
    if (n >= N) return;
    const float4* xr = (const float4*)(x + (size_t)n * 128);
    float acc[16];
    #pragma unroll
    for (int c = 0; c < 16; ++c) acc[c] = 0.f;
    for (int k4 = 0; k4 < 32; ++k4) {
        float4 a = xr[k4];
        #pragma unroll
        for (int c = 0; c < 16; ++c) {
            const float4 w = *(const float4*)&wsT[c * 132 + k4 * 4];
            acc[c] = fmaf(a.x, w.x, fmaf(a.y, w.y, fmaf(a.z, w.z, fmaf(a.w, w.w, acc[c]))));
        }
    }
    float dv = dinv[n];
    float4* o = (float4*)(ts + (size_t)n * 16);
    #pragma unroll
    for (int q = 0; q < 4; ++q)
        o[q] = make_float4(acc[4*q] * dv, acc[4*q+1] * dv, acc[4*q+2] * dv, acc[4*q+3] * dv);
}
__global__ void k_scatter(const int* __restrict__ row, const int* __restrict__ col,
                          const float* __restrict__ ts, float* __restrict__ acc, int E) {
    int g = blockIdx.x * 256 + threadIdx.x;
    int e = g >> 4, c = g & 15;
    if (e < E) atomicAdd(&acc[(size_t)col[e] * 16 + c], ts[(size_t)row[e] * 16 + c]);
}
__global__ void k_finalize(float* __restrict__ acc, const float* __restrict__ ts,
                           const float* __restrict__ dinv, const float* __restrict__ b,
                           int N, int relu) {
    int g = blockIdx.x * 256 + threadIdx.x;
    int v = g >> 4, c = g & 15;
    if (v < N) {
        float h = dinv[v] * (acc[g] + ts[g]) + b[c];
        if (relu) h = fmaxf(h, 0.f);
        acc[g] = h;
    }
}
__global__ __launch_bounds__(256) void k_gemm2f(
    const float* __restrict__ h1, const float* __restrict__ W2,
    const float* __restrict__ dinv, float* __restrict__ ts2, int N) {
    __shared__ float hs[16 * 17];
    __shared__ float ws2[256];
    const int tid = threadIdx.x;
    const int base = blockIdx.x * 16;
    if (tid < 64) ((float4*)ws2)[tid] = ((const float4*)W2)[tid];
    if (tid >= 64 && tid < 128) {
        int t2 = tid - 64;
        float4 v4 = ((const float4*)(h1 + (size_t)base * 16))[t2];
        float* d = &hs[(t2 >> 2) * 17 + (t2 & 3) * 4];
        d[0] = v4.x; d[1] = v4.y; d[2] = v4.z; d[3] = v4.w;
    }
    __syncthreads();
    const int r = tid >> 4, c = tid & 15;
    float a = 0.f;
    #pragma unroll
    for (int kk = 0; kk < 16; ++kk) a = fmaf(hs[r * 17 + kk], ws2[kk * 16 + c], a);
    ts2[(size_t)(base + r) * 16 + c] = a * dinv[base + r];
}
__global__ void k_scoref(const int* __restrict__ row, const int* __restrict__ col,
                         const float* __restrict__ h2, float* __restrict__ out, int E) {
    int e = blockIdx.x * 256 + threadIdx.x;
    if (e < E) {
        const float4* a = (const float4*)(h2 + (size_t)row[e] * 16);
        const float4* b = (const float4*)(h2 + (size_t)col[e] * 16);
        float d = 0.f;
        #pragma unroll
        for (int i = 0; i < 4; ++i) {
            float4 u = a[i], v = b[i];
            d += u.x * v.x + u.y * v.y + u.z * v.z + u.w * v.w;
        }
        out[e] = 1.0f / (1.0f + __expf(-d));
    }
}

extern "C" void kernel_launch(void* const* d_in, const int* in_sizes, int n_in,
                              void* d_out, int out_size, void* d_ws, size_t ws_size,
                              hipStream_t stream) {
    const float* x  = (const float*)d_in[0];
    const int*   ei = (const int*)d_in[1];
    const float* W1 = (const float*)d_in[2];
    const float* b1 = (const float*)d_in[3];
    const float* W2 = (const float*)d_in[4];
    const float* b2 = (const float*)d_in[5];

    const int N = in_sizes[0] / 128;   // 100000
    const int E = in_sizes[1] / 2;     // 3200000
    const int* row = ei;
    const int* col = ei + E;
    float* out = (float*)d_out;

    const int NBUK = (N + BSZ - 1) / BSZ;          // 196
    const int CN = (E + MAXCH - 1) / MAXCH;        // 1000 chunks
    const int CH = MAXCH;                          // 3200, multiple of 4

    char* ws = (char*)d_ws;
    size_t off = 0;
    auto alloc = [&](size_t bytes) { void* p = ws + off; off += (bytes + 255) & ~(size_t)255; return p; };
    float*  dinv  = (float*)alloc((size_t)N * 4);
    __half* ts1h  = (__half*)alloc((size_t)N * 32);    // also h2h after pGat1
    __half* ts2h  = (__half*)alloc((size_t)N * 32);
    int*    start = (int*)alloc((size_t)(N + 1) * 4);
    int*    M     = (int*)alloc((size_t)CN * NBUK * 4);
    int*    T     = (int*)alloc((size_t)NBUK * 4);
    int*    S     = (int*)alloc((size_t)(NBUK + 1) * 4);
    unsigned int* ebuf  = (unsigned int*)alloc((size_t)E * 4);
    unsigned int* ebuf2 = (unsigned int*)alloc((size_t)E * 4);
    const size_t need = off;    // ~34 MB at N=100k, E=3.2M

    if (N <= 131072 && NBUK <= 256 && CN <= MAXCHUNKS && ws_size >= need) {
        pA <<<CN, 512, 0, stream>>>(col, M, E, CH, NBUK);
        pB1<<<NBUK, 1024, 0, stream>>>(M, T, NBUK, CN);
        pB2<<<1, 512, 0, stream>>>(T, S, start, NBUK, N, E);
        pC <<<CN, 512, 0, stream>>>(row, col, M, S, ebuf, E, CH, NBUK);
        pC2<<<NBUK, 1024, 0, stream>>>(ebuf, S, ebuf2, dinv, start, N);
        k_gemm1<<<(N + 255) / 256, 256, 0, stream>>>(x, W1, dinv, ts1h, N);
        pGat1<<<(N + 31) / 32, 256, 0, stream>>>(ebuf2, start, (const __half2*)ts1h, dinv, b1, W2,
                                                 (__half2*)ts2h, N);
        __half* h2h = ts1h;   // ts1h dead after pGat1
        pGat2<<<(N + 31) / 32, 256, 0, stream>>>(ebuf2, start, (const __half2*)ts2h, dinv, b2,
                                                 (__half2*)h2h, N);
        k_score<<<(E + 255) / 256, 256, 0, stream>>>(row, col, h2h, out, E);
    } else {
        // R2 fallback, fp32 buffers carved independently
        float* dinvF = (float*)ws;
        float* ts1F  = (float*)(ws + (size_t)N * 4);
        float* ts2F  = (float*)(ws + (size_t)N * 4 + (size_t)N * 64);
        hipMemsetAsync(dinvF, 0, (size_t)N * 4, stream);
        hipMemsetAsync(ts2F, 0, (size_t)N * 64, stream);
        k_countf<<<(E + 255) / 256, 256, 0, stream>>>(col, dinvF, E);
        k_dinvf<<<(N + 255) / 256, 256, 0, stream>>>(dinvF, N);
        k_gemm1f<<<(N + 255) / 256, 256, 0, stream>>>(x, W1, dinvF, ts1F, N);
        k_scatter<<<(E * 16) / 256, 256, 0, stream>>>(row, col, ts1F, ts2F, E);
        k_finalize<<<(N * 16 + 255) / 256, 256, 0, stream>>>(ts2F, ts1F, dinvF, b1, N, 1);
        k_gemm2f<<<N / 16, 256, 0, stream>>>(ts2F, W2, dinvF, ts1F, N);
        hipMemsetAsync(ts2F, 0, (size_t)N * 64, stream);
        k_scatter<<<(E * 16) / 256, 256, 0, stream>>>(row, col, ts1F, ts2F, E);
        k_finalize<<<(N * 16 + 255) / 256, 256, 0, stream>>>(ts2F, ts1F, dinvF, b2, N, 0);
        k_scoref<<<(E + 255) / 256, 256, 0, stream>>>(row, col, ts2F, out, E);
    }
}